// Round 1
// baseline (2929.306 us; speedup 1.0000x reference)
//
#include <hip/hip_runtime.h>

#define B_SZ   2048
#define T_LEN  256
#define NBATCH 8     // samples per block
#define GRID   (B_SZ / NBATCH)   // 256 blocks, 1 per CU

__device__ __forceinline__ float fast_sigmoid(float x) {
    // 1/(1+exp(-x)) = 1/(1+exp2(-x*log2e))
    float e = __builtin_amdgcn_exp2f(x * -1.4426950408889634f);
    return __builtin_amdgcn_rcpf(1.0f + e);
}
__device__ __forceinline__ float fast_tanh(float x) {
    // tanh(x) = 2/(1+exp(-2x)) - 1
    float e = __builtin_amdgcn_exp2f(x * -2.8853900817779268f);
    return 2.0f * __builtin_amdgcn_rcpf(1.0f + e) - 1.0f;
}

// Fused 2-layer LSTM + FC head.
// Block of 512 threads handles NBATCH samples for the whole sequence.
//   threads [0,256)   : layer-0 gate rows (gate = tid)
//   threads [256,512) : layer-1 gate rows (gate = tid-256), skewed by 1 step
// Per-thread: W_ih row (64 f32) + W_hh row (64 f32) in registers.
__global__ __launch_bounds__(512, 2)
void lstm2_fused(const float* __restrict__ x,
                 const float* __restrict__ W_ih0, const float* __restrict__ W_hh0,
                 const float* __restrict__ b_ih0, const float* __restrict__ b_hh0,
                 const float* __restrict__ W_ih1, const float* __restrict__ W_hh1,
                 const float* __restrict__ b_ih1, const float* __restrict__ b_hh1,
                 const float* __restrict__ fc_w,  const float* __restrict__ fc_b,
                 float* __restrict__ out)
{
    const int tid = threadIdx.x;
    const int b0  = blockIdx.x * NBATCH;
    const bool isB = (tid >= 256);      // layer-1 half (wave-uniform)
    const int  g   = tid & 255;         // gate row 0..255

    const float* Wi = isB ? W_ih1 : W_ih0;
    const float* Wh = isB ? W_hh1 : W_hh0;
    const float bias = isB ? (b_ih1[g] + b_hh1[g]) : (b_ih0[g] + b_hh0[g]);

    // ---- weights into registers (fully unrolled -> VGPRs, not scratch) ----
    float wi[64], wh[64];
    {
        const float4* wi4 = reinterpret_cast<const float4*>(Wi + (size_t)g * 64);
        const float4* wh4 = reinterpret_cast<const float4*>(Wh + (size_t)g * 64);
        #pragma unroll
        for (int k = 0; k < 16; ++k) {
            float4 a = wi4[k], b = wh4[k];
            wi[4*k+0] = a.x; wi[4*k+1] = a.y; wi[4*k+2] = a.z; wi[4*k+3] = a.w;
            wh[4*k+0] = b.x; wh[4*k+1] = b.y; wh[4*k+2] = b.z; wh[4*k+3] = b.w;
        }
    }

    __shared__ __align__(16) float x_s [NBATCH][64];
    __shared__ __align__(16) float h1_s[NBATCH][64];
    __shared__ __align__(16) float c1_s[NBATCH][64];
    __shared__ __align__(16) float h2_s[NBATCH][64];
    __shared__ __align__(16) float c2_s[NBATCH][64];
    __shared__ __align__(16) float g1_s[NBATCH][256];
    __shared__ __align__(16) float g2_s[NBATCH][256];

    const int us = tid >> 6;   // 0..7 : sample slot for 1:1 item work
    const int uj = tid & 63;   // 0..63: hidden index

    // init state + preload x[0]
    h1_s[us][uj] = 0.0f; c1_s[us][uj] = 0.0f;
    h2_s[us][uj] = 0.0f; c2_s[us][uj] = 0.0f;
    x_s[us][uj] = x[((size_t)(b0 + us) * T_LEN + 0) * 64 + uj];
    __syncthreads();

    float (*in_s)[64]   = isB ? h1_s : x_s;   // "input" operand for this half
    float (*rec_s)[64]  = isB ? h2_s : h1_s;  // recurrent operand
    float (*go_s)[256]  = isB ? g2_s : g1_s;  // gate output buffer
    const bool g_is_tanh = (g >= 128 && g < 192);   // wave-uniform

    for (int u = 0; u <= T_LEN; ++u) {
        // ---------------- gate phase ----------------
        const bool active = isB ? (u >= 1) : (u < T_LEN);
        if (active) {
            float acc[NBATCH];
            #pragma unroll
            for (int s = 0; s < NBATCH; ++s) acc[s] = bias;
            #pragma unroll
            for (int k = 0; k < 16; ++k) {
                #pragma unroll
                for (int s = 0; s < NBATCH; ++s) {
                    float4 iv = *reinterpret_cast<const float4*>(&in_s[s][4*k]);
                    float4 rv = *reinterpret_cast<const float4*>(&rec_s[s][4*k]);
                    acc[s] += wi[4*k+0]*iv.x; acc[s] += wh[4*k+0]*rv.x;
                    acc[s] += wi[4*k+1]*iv.y; acc[s] += wh[4*k+1]*rv.y;
                    acc[s] += wi[4*k+2]*iv.z; acc[s] += wh[4*k+2]*rv.z;
                    acc[s] += wi[4*k+3]*iv.w; acc[s] += wh[4*k+3]*rv.w;
                }
            }
            if (g_is_tanh) {
                #pragma unroll
                for (int s = 0; s < NBATCH; ++s) go_s[s][g] = fast_tanh(acc[s]);
            } else {
                #pragma unroll
                for (int s = 0; s < NBATCH; ++s) go_s[s][g] = fast_sigmoid(acc[s]);
            }
        }
        // prefetch next x row into registers (hidden under gate compute)
        float x_next = 0.0f;
        const bool do_pref = (u + 1 < T_LEN);
        if (do_pref)
            x_next = x[((size_t)(b0 + us) * T_LEN + (u + 1)) * 64 + uj];

        __syncthreads();   // gates visible; x_s reads of step u are done

        // ---------------- update phase (every thread: item (us,uj), both layers) ----
        if (u < T_LEN) {
            float ig = g1_s[us][uj],      fg = g1_s[us][64 + uj];
            float gg = g1_s[us][128 + uj], og = g1_s[us][192 + uj];
            float c = fg * c1_s[us][uj] + ig * gg;
            float h = og * fast_tanh(c);
            c1_s[us][uj] = c; h1_s[us][uj] = h;
        }
        if (u >= 1) {
            float ig = g2_s[us][uj],      fg = g2_s[us][64 + uj];
            float gg = g2_s[us][128 + uj], og = g2_s[us][192 + uj];
            float c = fg * c2_s[us][uj] + ig * gg;
            float h = og * fast_tanh(c);
            c2_s[us][uj] = c; h2_s[us][uj] = h;
        }
        if (do_pref) x_s[us][uj] = x_next;

        __syncthreads();   // h/c/x_s ready for next gate phase
    }

    // ---------------- FC head: out[b] = dot(h2[T-1], fc_w) + fc_b --------------
    // wave w (= us) reduces sample us
    float v = h2_s[us][uj] * fc_w[uj];
    #pragma unroll
    for (int off = 32; off > 0; off >>= 1)
        v += __shfl_xor(v, off, 64);
    if (uj == 0) out[b0 + us] = v + fc_b[0];
}

extern "C" void kernel_launch(void* const* d_in, const int* in_sizes, int n_in,
                              void* d_out, int out_size, void* d_ws, size_t ws_size,
                              hipStream_t stream) {
    const float* x     = (const float*)d_in[0];
    const float* W_ih0 = (const float*)d_in[1];
    const float* W_hh0 = (const float*)d_in[2];
    const float* b_ih0 = (const float*)d_in[3];
    const float* b_hh0 = (const float*)d_in[4];
    const float* W_ih1 = (const float*)d_in[5];
    const float* W_hh1 = (const float*)d_in[6];
    const float* b_ih1 = (const float*)d_in[7];
    const float* b_hh1 = (const float*)d_in[8];
    const float* fc_w  = (const float*)d_in[9];
    const float* fc_b  = (const float*)d_in[10];
    float* out = (float*)d_out;

    lstm2_fused<<<GRID, 512, 0, stream>>>(x, W_ih0, W_hh0, b_ih0, b_hh0,
                                          W_ih1, W_hh1, b_ih1, b_hh1,
                                          fc_w, fc_b, out);
}

// Round 3
// 1308.580 us; speedup vs baseline: 2.2385x; 2.2385x over previous
//
#include <hip/hip_runtime.h>

typedef float f32x16 __attribute__((ext_vector_type(16)));

#define B_SZ   2048
#define T_LEN  256
#define NBATCH 8     // samples per block
#define GRID   (B_SZ / NBATCH)   // 256 blocks, 1 per CU

static __device__ __forceinline__ float fast_sigmoid(float x) {
    float e = __builtin_amdgcn_exp2f(x * -1.4426950408889634f);
    return __builtin_amdgcn_rcpf(1.0f + e);
}
static __device__ __forceinline__ float fast_tanh(float x) {
    float e = __builtin_amdgcn_exp2f(x * -2.8853900817779268f);
    return 2.0f * __builtin_amdgcn_rcpf(1.0f + e) - 1.0f;
}

// Gate phase for one layer-half: thread owns gate row g; weights live in
// f32x16 vectors (forced VGPR residency); operands broadcast from LDS.
static __device__ __forceinline__ void gate_phase(
    const f32x16 wiv[4], const f32x16 whv[4], float bias, bool g_is_tanh, int g,
    const float (*__restrict__ in_s)[64], const float (*__restrict__ rec_s)[64],
    float (*__restrict__ go_s)[256])
{
    float acc[NBATCH];
    #pragma unroll
    for (int s = 0; s < NBATCH; ++s) acc[s] = bias;

    #pragma unroll
    for (int q = 0; q < 4; ++q) {          // 4 chunks of 16 along K
        #pragma unroll
        for (int s = 0; s < NBATCH; ++s) {
            const float4* ip = reinterpret_cast<const float4*>(&in_s[s][q * 16]);
            const float4* rp = reinterpret_cast<const float4*>(&rec_s[s][q * 16]);
            #pragma unroll
            for (int t = 0; t < 4; ++t) {
                float4 iv = ip[t];
                float4 rv = rp[t];
                acc[s] = fmaf(wiv[q][4*t+0], iv.x, acc[s]);
                acc[s] = fmaf(whv[q][4*t+0], rv.x, acc[s]);
                acc[s] = fmaf(wiv[q][4*t+1], iv.y, acc[s]);
                acc[s] = fmaf(whv[q][4*t+1], rv.y, acc[s]);
                acc[s] = fmaf(wiv[q][4*t+2], iv.z, acc[s]);
                acc[s] = fmaf(whv[q][4*t+2], rv.z, acc[s]);
                acc[s] = fmaf(wiv[q][4*t+3], iv.w, acc[s]);
                acc[s] = fmaf(whv[q][4*t+3], rv.w, acc[s]);
            }
        }
    }
    if (g_is_tanh) {
        #pragma unroll
        for (int s = 0; s < NBATCH; ++s) go_s[s][g] = fast_tanh(acc[s]);
    } else {
        #pragma unroll
        for (int s = 0; s < NBATCH; ++s) go_s[s][g] = fast_sigmoid(acc[s]);
    }
}

__global__ __launch_bounds__(512, 2)
void lstm2_fused(const float* __restrict__ x,
                 const float* __restrict__ W_ih0, const float* __restrict__ W_hh0,
                 const float* __restrict__ b_ih0, const float* __restrict__ b_hh0,
                 const float* __restrict__ W_ih1, const float* __restrict__ W_hh1,
                 const float* __restrict__ b_ih1, const float* __restrict__ b_hh1,
                 const float* __restrict__ fc_w,  const float* __restrict__ fc_b,
                 float* __restrict__ out)
{
    const int tid = threadIdx.x;
    const int b0  = blockIdx.x * NBATCH;
    const bool isB = (tid >= 256);      // layer-1 half (wave-uniform)
    const int  g   = tid & 255;         // gate row 0..255

    const float* Wi = isB ? W_ih1 : W_ih0;
    const float* Wh = isB ? W_hh1 : W_hh0;
    const float bias = isB ? (b_ih1[g] + b_hh1[g]) : (b_ih0[g] + b_hh0[g]);

    // ---- weights into VGPRs via ext_vector_type (128 regs) ----
    f32x16 wiv[4], whv[4];
    {
        const float4* wi4 = reinterpret_cast<const float4*>(Wi + (size_t)g * 64);
        const float4* wh4 = reinterpret_cast<const float4*>(Wh + (size_t)g * 64);
        #pragma unroll
        for (int q = 0; q < 4; ++q) {
            #pragma unroll
            for (int t = 0; t < 4; ++t) {
                float4 a = wi4[q*4 + t];
                float4 b = wh4[q*4 + t];
                wiv[q][4*t+0] = a.x; wiv[q][4*t+1] = a.y;
                wiv[q][4*t+2] = a.z; wiv[q][4*t+3] = a.w;
                whv[q][4*t+0] = b.x; whv[q][4*t+1] = b.y;
                whv[q][4*t+2] = b.z; whv[q][4*t+3] = b.w;
            }
        }
    }

    __shared__ __align__(16) float x_s [NBATCH][64];
    __shared__ __align__(16) float h1_s[NBATCH][64];
    __shared__ __align__(16) float c1_s[NBATCH][64];
    __shared__ __align__(16) float h2_s[NBATCH][64];
    __shared__ __align__(16) float c2_s[NBATCH][64];
    __shared__ __align__(16) float g1_s[NBATCH][256];
    __shared__ __align__(16) float g2_s[NBATCH][256];

    const int us = tid >> 6;   // 0..7 : sample slot for 1:1 item work
    const int uj = tid & 63;   // 0..63: hidden index

    // init state + preload x[0]
    h1_s[us][uj] = 0.0f; c1_s[us][uj] = 0.0f;
    h2_s[us][uj] = 0.0f; c2_s[us][uj] = 0.0f;
    x_s[us][uj] = x[((size_t)(b0 + us) * T_LEN + 0) * 64 + uj];
    __syncthreads();

    const bool g_is_tanh = (g >= 128 && g < 192);   // wave-uniform

    for (int u = 0; u <= T_LEN; ++u) {
        // ---------------- gate phase (uniform branch per half) ----------------
        if (isB) {
            if (u >= 1)
                gate_phase(wiv, whv, bias, g_is_tanh, g, h1_s, h2_s, g2_s);
        } else {
            if (u < T_LEN)
                gate_phase(wiv, whv, bias, g_is_tanh, g, x_s, h1_s, g1_s);
        }

        // prefetch next x row into registers (hidden under gate compute)
        float x_next = 0.0f;
        const bool do_pref = (u + 1 < T_LEN);
        if (do_pref)
            x_next = x[((size_t)(b0 + us) * T_LEN + (u + 1)) * 64 + uj];

        __syncthreads();   // gates visible; x_s reads of step u are done

        // ---------------- update phase (every thread: item (us,uj), both layers) ----
        if (u < T_LEN) {
            float ig = g1_s[us][uj],       fg = g1_s[us][64 + uj];
            float gg = g1_s[us][128 + uj], og = g1_s[us][192 + uj];
            float c = fg * c1_s[us][uj] + ig * gg;
            float h = og * fast_tanh(c);
            c1_s[us][uj] = c; h1_s[us][uj] = h;
        }
        if (u >= 1) {
            float ig = g2_s[us][uj],       fg = g2_s[us][64 + uj];
            float gg = g2_s[us][128 + uj], og = g2_s[us][192 + uj];
            float c = fg * c2_s[us][uj] + ig * gg;
            float h = og * fast_tanh(c);
            c2_s[us][uj] = c; h2_s[us][uj] = h;
        }
        if (do_pref) x_s[us][uj] = x_next;

        __syncthreads();   // h/c/x_s ready for next gate phase
    }

    // ---------------- FC head: out[b] = dot(h2[T-1], fc_w) + fc_b --------------
    float v = h2_s[us][uj] * fc_w[uj];
    #pragma unroll
    for (int off = 32; off > 0; off >>= 1)
        v += __shfl_xor(v, off, 64);
    if (uj == 0) out[b0 + us] = v + fc_b[0];
}

extern "C" void kernel_launch(void* const* d_in, const int* in_sizes, int n_in,
                              void* d_out, int out_size, void* d_ws, size_t ws_size,
                              hipStream_t stream) {
    const float* x     = (const float*)d_in[0];
    const float* W_ih0 = (const float*)d_in[1];
    const float* W_hh0 = (const float*)d_in[2];
    const float* b_ih0 = (const float*)d_in[3];
    const float* b_hh0 = (const float*)d_in[4];
    const float* W_ih1 = (const float*)d_in[5];
    const float* W_hh1 = (const float*)d_in[6];
    const float* b_ih1 = (const float*)d_in[7];
    const float* b_hh1 = (const float*)d_in[8];
    const float* fc_w  = (const float*)d_in[9];
    const float* fc_b  = (const float*)d_in[10];
    float* out = (float*)d_out;

    lstm2_fused<<<GRID, 512, 0, stream>>>(x, W_ih0, W_hh0, b_ih0, b_hh0,
                                          W_ih1, W_hh1, b_ih1, b_hh1,
                                          fc_w, fc_b, out);
}

// Round 4
// 417.890 us; speedup vs baseline: 7.0097x; 3.1314x over previous
//
#include <hip/hip_runtime.h>

typedef short short8 __attribute__((ext_vector_type(8)));
typedef float f32x4  __attribute__((ext_vector_type(4)));
typedef unsigned short u16;

#define T_LEN 256
#define NB    8            // real samples per block
#define GRID  (2048 / NB)  // 256 blocks
#define LDK   136          // padded operand row stride in bf16 elems (272 B)

static __device__ __forceinline__ u16 bf16_hi(float f) {
    unsigned u = __builtin_bit_cast(unsigned, f);
    return (u16)((u + 0x7fffu + ((u >> 16) & 1u)) >> 16);   // RNE f32->bf16
}
static __device__ __forceinline__ float bf16_f(u16 h) {
    unsigned u = ((unsigned)h) << 16;
    return __builtin_bit_cast(float, u);
}
static __device__ __forceinline__ float fast_sigmoid(float x) {
    float e = __builtin_amdgcn_exp2f(x * -1.4426950408889634f);
    return __builtin_amdgcn_rcpf(1.0f + e);
}
static __device__ __forceinline__ float fast_tanh(float x) {
    float e = __builtin_amdgcn_exp2f(x * -2.8853900817779268f);
    return 2.0f * __builtin_amdgcn_rcpf(1.0f + e) - 1.0f;
}

// ---------------------------------------------------------------------------
// Fused 2-layer LSTM + FC via split-bf16 MFMA.
// Per step, per layer: gates[256][8] = Wperm[256][128] @ B[128][16(8 real)]
// Wperm row order: (wave w, mtile mt, tile-row tr): unit = w*8+mt*4+(tr>>2),
// gate = tr&3, source row = gate*64 + unit. MFMA C layout (col=lane&15,
// row=(lane>>4)*4+reg) then gives lane (kg,s) acc[r] = gate r of unit
// w*8+mt*4+kg for sample s — all 4 gates in-lane, no exchange.
// Operands staged in LDS as bf16 hi/lo rows [n][K], parity double-buffered.
// ---------------------------------------------------------------------------
__global__ __launch_bounds__(512, 2)
void lstm2_mfma(const float* __restrict__ x,
                const float* __restrict__ W_ih0, const float* __restrict__ W_hh0,
                const float* __restrict__ b_ih0, const float* __restrict__ b_hh0,
                const float* __restrict__ W_ih1, const float* __restrict__ W_hh1,
                const float* __restrict__ b_ih1, const float* __restrict__ b_hh1,
                const float* __restrict__ fc_w,  const float* __restrict__ fc_b,
                float* __restrict__ out)
{
    const int tid = threadIdx.x;
    const int l   = tid & 63;      // lane
    const int w   = tid >> 6;      // wave 0..7
    const int ln  = l & 15;        // frag row index / C col (sample)
    const int kg  = l >> 4;        // 0..3

    // [parity][arr: 0=B0hi 1=B0lo 2=B1hi 3=B1lo][n=16][LDK]
    __shared__ __align__(16) u16 Bls[2][4][16][LDK];
    __shared__ __align__(16) float hfin[NB][68];

    // ---- A fragments (permuted weights, bf16 hi/lo) + biases ----
    short8 Ah[2][2][4], Al[2][2][4];   // [layer][mt][kt]
    f32x4  biasv[2][2];
    #pragma unroll
    for (int L = 0; L < 2; ++L) {
        const float* Wi = L ? W_ih1 : W_ih0;
        const float* Wh = L ? W_hh1 : W_hh0;
        const float* bi = L ? b_ih1 : b_ih0;
        const float* bh = L ? b_hh1 : b_hh0;
        #pragma unroll
        for (int mt = 0; mt < 2; ++mt) {
            #pragma unroll
            for (int kt = 0; kt < 4; ++kt) {
                const int uu   = ln >> 2;
                const int gate = ln & 3;
                const int row  = gate * 64 + ((w << 3) + (mt << 2) + uu);
                const int kb   = kt * 32 + kg * 8;    // k in [Wih | Whh]
                const float* src = (kb < 64) ? (Wi + (size_t)row * 64 + kb)
                                             : (Wh + (size_t)row * 64 + (kb - 64));
                short8 h8, l8;
                #pragma unroll
                for (int j = 0; j < 8; ++j) {
                    float v  = src[j];
                    u16  hh  = bf16_hi(v);
                    u16  ll  = bf16_hi(v - bf16_f(hh));
                    h8[j] = (short)hh;
                    l8[j] = (short)ll;
                }
                Ah[L][mt][kt] = h8;
                Al[L][mt][kt] = l8;
            }
            f32x4 bv;
            #pragma unroll
            for (int r = 0; r < 4; ++r) {
                const int row = r * 64 + ((w << 3) + (mt << 2) + kg);
                bv[r] = bi[row] + bh[row];
            }
            biasv[L][mt] = bv;
        }
    }

    // ---- zero operand LDS (both parities; junk rows 8..15 stay 0) ----
    {
        u16* pz = &Bls[0][0][0][0];
        const int tot = 2 * 4 * 16 * LDK;
        for (int i = tid; i < tot; i += 512) pz[i] = 0;
    }
    __syncthreads();

    const int    sb    = blockIdx.x * NB;
    const int    xs    = tid >> 6;   // sample slot for x staging
    const int    xj    = tid & 63;   // k index for x staging
    const size_t xbase = ((size_t)(sb + xs)) * T_LEN * 64 + xj;

    {   // stage x(t=0) into B0[0]
        float x0 = x[xbase];
        u16 hh = bf16_hi(x0), ll = bf16_hi(x0 - bf16_f(hh));
        Bls[0][0][xs][xj] = hh;
        Bls[0][1][xs][xj] = ll;
    }
    __syncthreads();

    float c1[2] = {0.f, 0.f}, c2[2] = {0.f, 0.f};
    float xcur = x[xbase + 64];      // x(t=1)

#define MFMA(A, B, C) __builtin_amdgcn_mfma_f32_16x16x32_bf16(A, B, C, 0, 0, 0)

    #pragma unroll 1
    for (int u = 0; u < T_LEN; ++u) {
        const int p = u & 1, q = p ^ 1;
        float xnext = 0.f;
        if (u + 2 < T_LEN) xnext = x[xbase + (size_t)(u + 2) * 64];

        // ================= phase A : layer 0  (B operand = [x_t | h1_{t-1}])
        f32x4 a0 = biasv[0][0], a1 = biasv[0][1];
        #pragma unroll
        for (int kt = 0; kt < 4; ++kt) {
            short8 bh = *(const short8*)&Bls[p][0][ln][kt * 32 + kg * 8];
            short8 bl = *(const short8*)&Bls[p][1][ln][kt * 32 + kg * 8];
            a0 = MFMA(Ah[0][0][kt], bh, a0);
            a1 = MFMA(Ah[0][1][kt], bh, a1);
            a0 = MFMA(Al[0][0][kt], bh, a0);
            a1 = MFMA(Al[0][1][kt], bh, a1);
            a0 = MFMA(Ah[0][0][kt], bl, a0);
            a1 = MFMA(Ah[0][1][kt], bl, a1);
        }
        #pragma unroll
        for (int mt = 0; mt < 2; ++mt) {
            const f32x4 ac = mt ? a1 : a0;
            const float ig = fast_sigmoid(ac[0]);
            const float fg = fast_sigmoid(ac[1]);
            const float gg = fast_tanh(ac[2]);
            const float og = fast_sigmoid(ac[3]);
            const float c  = fg * c1[mt] + ig * gg;
            c1[mt] = c;
            const float h = og * fast_tanh(c);
            if (ln < 8) {
                const int un = (w << 3) + (mt << 2) + kg;
                const u16 hh = bf16_hi(h);
                const u16 ll = bf16_hi(h - bf16_f(hh));
                Bls[p][2][ln][un] = hh;        // B1[p] h1-half (read phase B this step)
                Bls[p][3][ln][un] = ll;
                Bls[q][0][ln][64 + un] = hh;   // B0[q] h1-half (next step)
                Bls[q][1][ln][64 + un] = ll;
            }
        }
        if (u + 1 < T_LEN) {                   // stage x_{u+1} into B0[q]
            const u16 hh = bf16_hi(xcur);
            const u16 ll = bf16_hi(xcur - bf16_f(hh));
            Bls[q][0][xs][xj] = hh;
            Bls[q][1][xs][xj] = ll;
        }
        xcur = xnext;
        __syncthreads();

        // ================= phase B : layer 1  (B operand = [h1_t | h2_{t-1}])
        f32x4 g0 = biasv[1][0], g1 = biasv[1][1];
        #pragma unroll
        for (int kt = 0; kt < 4; ++kt) {
            short8 bh = *(const short8*)&Bls[p][2][ln][kt * 32 + kg * 8];
            short8 bl = *(const short8*)&Bls[p][3][ln][kt * 32 + kg * 8];
            g0 = MFMA(Ah[1][0][kt], bh, g0);
            g1 = MFMA(Ah[1][1][kt], bh, g1);
            g0 = MFMA(Al[1][0][kt], bh, g0);
            g1 = MFMA(Al[1][1][kt], bh, g1);
            g0 = MFMA(Ah[1][0][kt], bl, g0);
            g1 = MFMA(Ah[1][1][kt], bl, g1);
        }
        #pragma unroll
        for (int mt = 0; mt < 2; ++mt) {
            const f32x4 ac = mt ? g1 : g0;
            const float ig = fast_sigmoid(ac[0]);
            const float fg = fast_sigmoid(ac[1]);
            const float gg = fast_tanh(ac[2]);
            const float og = fast_sigmoid(ac[3]);
            const float c  = fg * c2[mt] + ig * gg;
            c2[mt] = c;
            const float h = og * fast_tanh(c);
            if (ln < 8) {
                const int un = (w << 3) + (mt << 2) + kg;
                const u16 hh = bf16_hi(h);
                const u16 ll = bf16_hi(h - bf16_f(hh));
                Bls[q][2][ln][64 + un] = hh;   // B1[q] h2-half (next step)
                Bls[q][3][ln][64 + un] = ll;
                if (u == T_LEN - 1) hfin[ln][un] = h;
            }
        }
        __syncthreads();
    }
#undef MFMA

    // ---- FC head: wave w reduces sample w ----
    const float v0 = hfin[w][l] * fc_w[l];
    float v = v0;
    #pragma unroll
    for (int off = 32; off; off >>= 1) v += __shfl_xor(v, off, 64);
    if (l == 0) out[sb + w] = v + fc_b[0];
}

extern "C" void kernel_launch(void* const* d_in, const int* in_sizes, int n_in,
                              void* d_out, int out_size, void* d_ws, size_t ws_size,
                              hipStream_t stream) {
    const float* x     = (const float*)d_in[0];
    const float* W_ih0 = (const float*)d_in[1];
    const float* W_hh0 = (const float*)d_in[2];
    const float* b_ih0 = (const float*)d_in[3];
    const float* b_hh0 = (const float*)d_in[4];
    const float* W_ih1 = (const float*)d_in[5];
    const float* W_hh1 = (const float*)d_in[6];
    const float* b_ih1 = (const float*)d_in[7];
    const float* b_hh1 = (const float*)d_in[8];
    const float* fc_w  = (const float*)d_in[9];
    const float* fc_b  = (const float*)d_in[10];
    float* out = (float*)d_out;

    lstm2_mfma<<<GRID, 512, 0, stream>>>(x, W_ih0, W_hh0, b_ih0, b_hh0,
                                         W_ih1, W_hh1, b_ih1, b_hh1,
                                         fc_w, fc_b, out);
}

// Round 5
// 410.504 us; speedup vs baseline: 7.1359x; 1.0180x over previous
//
#include <hip/hip_runtime.h>

typedef short short8 __attribute__((ext_vector_type(8)));
typedef float f32x4  __attribute__((ext_vector_type(4)));
typedef unsigned short u16;

#define T_LEN 256
#define NB    8            // samples per block
#define GRID  (2048 / NB)  // 256 blocks, 1/CU
#define LDK   136          // operand row stride in u16 (272 B = 17 × 16 B)

static __device__ __forceinline__ u16 bf16_rne(float f) {
    unsigned u = __builtin_bit_cast(unsigned, f);
    return (u16)((u + 0x7fffu + ((u >> 16) & 1u)) >> 16);
}
static __device__ __forceinline__ float bf16_f(u16 h) {
    unsigned u = ((unsigned)h) << 16;
    return __builtin_bit_cast(float, u);
}
// exact trunc split: f == bf16(hi) + rest, lo = trunc-bf16(rest); err ~2^-16
static __device__ __forceinline__ void split_tr(float f, u16& hi, u16& lo) {
    unsigned u = __builtin_bit_cast(unsigned, f);
    hi = (u16)(u >> 16);
    float rest = f - __builtin_bit_cast(float, u & 0xffff0000u);
    lo = (u16)(__builtin_bit_cast(unsigned, rest) >> 16);
}
static __device__ __forceinline__ float fast_sigmoid(float x) {
    float e = __builtin_amdgcn_exp2f(x * -1.4426950408889634f);
    return __builtin_amdgcn_rcpf(1.0f + e);
}
static __device__ __forceinline__ float fast_tanh(float x) {
    float e = __builtin_amdgcn_exp2f(x * -2.8853900817779268f);
    return 2.0f * __builtin_amdgcn_rcpf(1.0f + e) - 1.0f;
}

// ---------------------------------------------------------------------------
// Wave-specialized fused 2-layer LSTM + FC, split-bf16 MFMA.
// Waves 0-3: layer 0, step t   (B operand XH[p] = [x(t) | h1(t-1)])
// Waves 4-7: layer 1, step t-1 (B operand HH[p] = [h1(t-1) | h2(t-2)])
// One barrier per combined phase; reads hit parity p, writes parity q=p^1.
// Each wave owns 16 units x 4 gates = 64 rows (4 mtiles), weights in VGPRs.
// C layout (col=lane&15=sample, row=(lane>>4)*4+reg): permuted weight rows
// (row = gate*64 + unit, unit = wl*16 + mt*4 + (tr>>2), gate = tr&3) make
// acc[r] = gate r of unit wl*16+mt*4+kg -- all 4 gates in-lane.
// ---------------------------------------------------------------------------
__global__ __launch_bounds__(512, 2)
void lstm2_mfma(const float* __restrict__ x,
                const float* __restrict__ W_ih0, const float* __restrict__ W_hh0,
                const float* __restrict__ b_ih0, const float* __restrict__ b_hh0,
                const float* __restrict__ W_ih1, const float* __restrict__ W_hh1,
                const float* __restrict__ b_ih1, const float* __restrict__ b_hh1,
                const float* __restrict__ fc_w,  const float* __restrict__ fc_b,
                float* __restrict__ out)
{
    const int tid = threadIdx.x;
    const int l   = tid & 63;
    const int w   = tid >> 6;      // wave 0..7
    const int grp = w >> 2;        // 0 = layer0, 1 = layer1
    const int wl  = w & 3;         // wave-in-group
    const int ln  = l & 15;        // sample col / frag row
    const int kg  = l >> 4;        // 0..3

    __shared__ __align__(16) u16 XH[2][2][16][LDK];   // [parity][hi/lo][row][k]
    __shared__ __align__(16) u16 HH[2][2][16][LDK];
    __shared__ __align__(16) float hfin[NB][68];

    // ---- A fragments (my layer only): [mt=4][kt=4], RNE hi + exact lo ----
    short8 Ah[4][4], Al[4][4];
    f32x4  biasv[4];
    {
        const float* Wi = grp ? W_ih1 : W_ih0;
        const float* Wh = grp ? W_hh1 : W_hh0;
        const float* bi = grp ? b_ih1 : b_ih0;
        const float* bh = grp ? b_hh1 : b_hh0;
        #pragma unroll
        for (int mt = 0; mt < 4; ++mt) {
            #pragma unroll
            for (int kt = 0; kt < 4; ++kt) {
                const int uu   = ln >> 2;
                const int gate = ln & 3;
                const int row  = gate * 64 + (wl * 16 + mt * 4 + uu);
                const int kb   = kt * 32 + kg * 8;
                const float* src = (kb < 64) ? (Wi + (size_t)row * 64 + kb)
                                             : (Wh + (size_t)row * 64 + (kb - 64));
                short8 h8, l8;
                #pragma unroll
                for (int j = 0; j < 8; ++j) {
                    float v = src[j];
                    u16 hh = bf16_rne(v);
                    u16 ll = bf16_rne(v - bf16_f(hh));
                    h8[j] = (short)hh; l8[j] = (short)ll;
                }
                Ah[mt][kt] = h8; Al[mt][kt] = l8;
            }
            f32x4 bv;
            #pragma unroll
            for (int r = 0; r < 4; ++r) {
                const int row = r * 64 + (wl * 16 + mt * 4 + kg);
                bv[r] = bi[row] + bh[row];
            }
            biasv[mt] = bv;
        }
    }

    // ---- zero operand LDS (rows 8..15 must stay 0 forever) ----
    {
        u16* p0 = &XH[0][0][0][0];
        u16* p1 = &HH[0][0][0][0];
        const int tot = 2 * 2 * 16 * LDK;
        for (int i = tid; i < tot; i += 512) { p0[i] = 0; p1[i] = 0; }
    }
    __syncthreads();

    const int    sb    = blockIdx.x * NB;
    const int    xs    = tid >> 6;
    const int    xj    = tid & 63;
    const size_t xbase = ((size_t)(sb + xs)) * T_LEN * 64 + xj;

    {   // stage x(0) into XH[0]
        u16 hh, ll; split_tr(x[xbase], hh, ll);
        XH[0][0][xs][xj] = hh; XH[0][1][xs][xj] = ll;
    }
    __syncthreads();

    float cst[4] = {0.f, 0.f, 0.f, 0.f};
    float xcur = x[xbase + 64];      // x(1)

#define MFMA(A, B, C) __builtin_amdgcn_mfma_f32_16x16x32_bf16(A, B, C, 0, 0, 0)

    #pragma unroll 1
    for (int t = 0; t <= T_LEN; ++t) {
        const int p = t & 1, q = p ^ 1;
        float xnext = 0.f;
        if (t + 2 < T_LEN) xnext = x[xbase + (size_t)(t + 2) * 64];

        const bool active = grp ? (t >= 1) : (t < T_LEN);
        if (active) {
            const u16 (*Bhv)[LDK] = grp ? HH[p][0] : XH[p][0];
            const u16 (*Blv)[LDK] = grp ? HH[p][1] : XH[p][1];
            short8 bh[4], bl[4];
            #pragma unroll
            for (int kt = 0; kt < 4; ++kt) {
                bh[kt] = *(const short8*)&Bhv[ln][kt * 32 + kg * 8];
                bl[kt] = *(const short8*)&Blv[ln][kt * 32 + kg * 8];
            }
            #pragma unroll
            for (int mt = 0; mt < 4; ++mt) {
                f32x4 aA = biasv[mt];
                f32x4 aB = {0.f, 0.f, 0.f, 0.f};
                f32x4 aC = {0.f, 0.f, 0.f, 0.f};
                #pragma unroll
                for (int kt = 0; kt < 4; ++kt) {
                    aA = MFMA(Ah[mt][kt], bh[kt], aA);
                    aB = MFMA(Al[mt][kt], bh[kt], aB);
                    aC = MFMA(Ah[mt][kt], bl[kt], aC);
                }
                const f32x4 ac = aA + aB + aC;
                const float ig = fast_sigmoid(ac[0]);
                const float fg = fast_sigmoid(ac[1]);
                const float gg = fast_tanh(ac[2]);
                const float og = fast_sigmoid(ac[3]);
                const float cc = fg * cst[mt] + ig * gg;
                cst[mt] = cc;
                const float hv = og * fast_tanh(cc);

                if (ln < 8) {
                    const int un = wl * 16 + mt * 4 + kg;
                    u16 hh, ll; split_tr(hv, hh, ll);
                    if (grp == 0) {
                        XH[q][0][ln][64 + un] = hh;   // h1 for layer 0, next step
                        XH[q][1][ln][64 + un] = ll;
                        HH[q][0][ln][un]      = hh;   // h1 for layer 1, next phase
                        HH[q][1][ln][un]      = ll;
                    } else {
                        HH[q][0][ln][64 + un] = hh;   // h2 recurrent
                        HH[q][1][ln][64 + un] = ll;
                        if (t == T_LEN) hfin[ln][un] = hv;
                    }
                }
            }
        }

        if (t + 1 < T_LEN) {          // stage x(t+1) into XH[q]
            u16 hh, ll; split_tr(xcur, hh, ll);
            XH[q][0][xs][xj] = hh; XH[q][1][xs][xj] = ll;
        }
        xcur = xnext;
        __syncthreads();
    }
#undef MFMA

    // ---- FC head: wave w reduces sample w ----
    float v = hfin[w][l] * fc_w[l];
    #pragma unroll
    for (int off = 32; off; off >>= 1) v += __shfl_xor(v, off, 64);
    if (l == 0) out[sb + w] = v + fc_b[0];
}

extern "C" void kernel_launch(void* const* d_in, const int* in_sizes, int n_in,
                              void* d_out, int out_size, void* d_ws, size_t ws_size,
                              hipStream_t stream) {
    const float* x     = (const float*)d_in[0];
    const float* W_ih0 = (const float*)d_in[1];
    const float* W_hh0 = (const float*)d_in[2];
    const float* b_ih0 = (const float*)d_in[3];
    const float* b_hh0 = (const float*)d_in[4];
    const float* W_ih1 = (const float*)d_in[5];
    const float* W_hh1 = (const float*)d_in[6];
    const float* b_ih1 = (const float*)d_in[7];
    const float* b_hh1 = (const float*)d_in[8];
    const float* fc_w  = (const float*)d_in[9];
    const float* fc_b  = (const float*)d_in[10];
    float* out = (float*)d_out;

    lstm2_mfma<<<GRID, 512, 0, stream>>>(x, W_ih0, W_hh0, b_ih0, b_hh0,
                                         W_ih1, W_hh1, b_ih1, b_hh1,
                                         fc_w, fc_b, out);
}

// Round 6
// 311.205 us; speedup vs baseline: 9.4128x; 1.3191x over previous
//
#include <hip/hip_runtime.h>

typedef short short8 __attribute__((ext_vector_type(8)));
typedef float f32x4  __attribute__((ext_vector_type(4)));
typedef unsigned short u16;

#define T_LEN 256
#define NB    8            // samples per block
#define GRID  (2048 / NB)  // 256 blocks, 1/CU
#define LDK   136          // operand row stride in u16 (272 B)

static __device__ __forceinline__ u16 bf16_rne(float f) {
    unsigned u = __builtin_bit_cast(unsigned, f);
    return (u16)((u + 0x7fffu + ((u >> 16) & 1u)) >> 16);
}
static __device__ __forceinline__ float bf16_f(u16 h) {
    unsigned u = ((unsigned)h) << 16;
    return __builtin_bit_cast(float, u);
}
// exact trunc split: f == bf16(hi) + rest; lo = trunc-bf16(rest)
static __device__ __forceinline__ void split_tr(float f, u16& hi, u16& lo) {
    unsigned u = __builtin_bit_cast(unsigned, f);
    hi = (u16)(u >> 16);
    float rest = f - __builtin_bit_cast(float, u & 0xffff0000u);
    lo = (u16)(__builtin_bit_cast(unsigned, rest) >> 16);
}
static __device__ __forceinline__ float fast_sigmoid(float x) {
    float e = __builtin_amdgcn_exp2f(x * -1.4426950408889634f);
    return __builtin_amdgcn_rcpf(1.0f + e);
}
static __device__ __forceinline__ float fast_tanh(float x) {
    float e = __builtin_amdgcn_exp2f(x * -2.8853900817779268f);
    return 2.0f * __builtin_amdgcn_rcpf(1.0f + e) - 1.0f;
}

// ---------------------------------------------------------------------------
// 16-wave wave-specialized fused 2-layer LSTM + FC, split-bf16 MFMA.
// Waves 0-7 : layer 0, step t   (B = XH[p] = [x(t) | h1(t-1)])
// Waves 8-15: layer 1, step t-1 (B = HH[p] = [h1(t-1) | h2(t-2)])
// Each wave: 2 mtiles = 8 units (base wl*8), weights 64 VGPR.
// Row permutation (verified r4/r5): row = gate*64 + unit, unit = wl*8+mt*4+uu,
// uu = ln>>2, gate = ln&3. C layout: col=ln=sample, acc[r] = gate r of unit
// wl*8+mt*4+kg.  After MFMA, mt1's real cols (ln<8) are packed into mt0's
// junk lanes (ln>=8) via shfl_xor(8): one full-lane activation pass per wave;
// lane identity = (sample ln&7, unit wl*8 + ((ln>>3)&1)*4 + kg).
// ---------------------------------------------------------------------------
__global__ __launch_bounds__(1024)
void lstm2_mfma(const float* __restrict__ x,
                const float* __restrict__ W_ih0, const float* __restrict__ W_hh0,
                const float* __restrict__ b_ih0, const float* __restrict__ b_hh0,
                const float* __restrict__ W_ih1, const float* __restrict__ W_hh1,
                const float* __restrict__ b_ih1, const float* __restrict__ b_hh1,
                const float* __restrict__ fc_w,  const float* __restrict__ fc_b,
                float* __restrict__ out)
{
    const int tid = threadIdx.x;
    const int l   = tid & 63;
    const int w   = tid >> 6;      // wave 0..15
    const int grp = w >> 3;        // 0 = layer0, 1 = layer1
    const int wl  = w & 7;         // wave-in-group 0..7
    const int ln  = l & 15;        // C col / frag row
    const int kg  = l >> 4;        // 0..3

    __shared__ __align__(16) u16 XH[2][2][16][LDK];   // [parity][hi/lo][row][k]
    __shared__ __align__(16) u16 HH[2][2][16][LDK];
    __shared__ __align__(16) float hfin[NB][68];

    // ---- A fragments (my layer, 2 mtiles): RNE hi + lo ----
    short8 Ah[2][4], Al[2][4];
    f32x4  biasv[2];
    {
        const float* Wi = grp ? W_ih1 : W_ih0;
        const float* Wh = grp ? W_hh1 : W_hh0;
        const float* bi = grp ? b_ih1 : b_ih0;
        const float* bh = grp ? b_hh1 : b_hh0;
        #pragma unroll
        for (int mt = 0; mt < 2; ++mt) {
            #pragma unroll
            for (int kt = 0; kt < 4; ++kt) {
                const int uu   = ln >> 2;
                const int gate = ln & 3;
                const int row  = gate * 64 + (wl * 8 + mt * 4 + uu);
                const int kb   = kt * 32 + kg * 8;
                const float* src = (kb < 64) ? (Wi + (size_t)row * 64 + kb)
                                             : (Wh + (size_t)row * 64 + (kb - 64));
                short8 h8, l8;
                #pragma unroll
                for (int j = 0; j < 8; ++j) {
                    float v = src[j];
                    u16 hh = bf16_rne(v);
                    u16 ll = bf16_rne(v - bf16_f(hh));
                    h8[j] = (short)hh; l8[j] = (short)ll;
                }
                Ah[mt][kt] = h8; Al[mt][kt] = l8;
            }
            f32x4 bv;
            #pragma unroll
            for (int r = 0; r < 4; ++r) {
                const int row = r * 64 + (wl * 8 + mt * 4 + kg);
                bv[r] = bi[row] + bh[row];
            }
            biasv[mt] = bv;
        }
    }

    // ---- zero operand LDS (rows 8..15 stay 0 forever) ----
    {
        u16* p0 = &XH[0][0][0][0];
        u16* p1 = &HH[0][0][0][0];
        const int tot = 2 * 2 * 16 * LDK;
        for (int i = tid; i < tot; i += 1024) { p0[i] = 0; p1[i] = 0; }
    }
    __syncthreads();

    const int    sb    = blockIdx.x * NB;
    const int    xs    = (tid >> 6) & 7;   // staging sample (threads 0..511)
    const int    xj    = tid & 63;
    const bool   stg   = (tid < 512);      // wave-uniform
    const size_t xbase = ((size_t)(sb + xs)) * T_LEN * 64 + xj;

    if (stg) {   // stage x(0) into XH[0]
        u16 hh, ll; split_tr(x[xbase], hh, ll);
        XH[0][0][xs][xj] = hh; XH[0][1][xs][xj] = ll;
    }
    __syncthreads();

    // packed-lane identity for activations/updates
    const int  mtl  = (ln >> 3) & 1;       // 0: mt0 value, 1: mt1 value
    const int  smp  = ln & 7;              // sample
    const int  un   = wl * 8 + mtl * 4 + kg;
    const bool lo8  = (ln < 8);
    float cstate = 0.f;
    float xcur = stg ? x[xbase + 64] : 0.f;   // x(1)

#define MFMA(A, B, C) __builtin_amdgcn_mfma_f32_16x16x32_bf16(A, B, C, 0, 0, 0)

    #pragma unroll 1
    for (int t = 0; t <= T_LEN; ++t) {
        const int p = t & 1, q = p ^ 1;
        float xnext = 0.f;
        if (stg && t + 2 < T_LEN) xnext = x[xbase + (size_t)(t + 2) * 64];

        const bool active = grp ? (t >= 1) : (t < T_LEN);
        if (active) {
            const u16 (*Bhv)[LDK] = grp ? HH[p][0] : XH[p][0];
            const u16 (*Blv)[LDK] = grp ? HH[p][1] : XH[p][1];
            short8 bh[4], bl[4];
            #pragma unroll
            for (int kt = 0; kt < 4; ++kt) {
                bh[kt] = *(const short8*)&Bhv[ln][kt * 32 + kg * 8];
                bl[kt] = *(const short8*)&Blv[ln][kt * 32 + kg * 8];
            }
            // chained accumulators (3 products per kt, bias pre-loaded)
            f32x4 a0 = biasv[0], a1 = biasv[1];
            #pragma unroll
            for (int kt = 0; kt < 4; ++kt) {
                a0 = MFMA(Ah[0][kt], bh[kt], a0);
                a1 = MFMA(Ah[1][kt], bh[kt], a1);
                a0 = MFMA(Al[0][kt], bh[kt], a0);
                a1 = MFMA(Al[1][kt], bh[kt], a1);
                a0 = MFMA(Ah[0][kt], bl[kt], a0);
                a1 = MFMA(Ah[1][kt], bl[kt], a1);
            }
            // pack mt1 real cols into mt0 junk lanes: one full-lane pass
            f32x4 pk;
            #pragma unroll
            for (int r = 0; r < 4; ++r) {
                float o = __shfl_xor(a1[r], 8, 64);
                pk[r] = lo8 ? a0[r] : o;
            }
            const float ig = fast_sigmoid(pk[0]);
            const float fg = fast_sigmoid(pk[1]);
            const float gg = fast_tanh(pk[2]);
            const float og = fast_sigmoid(pk[3]);
            const float cc = fg * cstate + ig * gg;
            cstate = cc;
            const float hv = og * fast_tanh(cc);

            u16 hh, ll; split_tr(hv, hh, ll);
            if (grp == 0) {
                XH[q][0][smp][64 + un] = hh;   // h1 recurrent (layer 0, t+1)
                XH[q][1][smp][64 + un] = ll;
                HH[q][0][smp][un]      = hh;   // h1 input (layer 1, t+1)
                HH[q][1][smp][un]      = ll;
            } else {
                HH[q][0][smp][64 + un] = hh;   // h2 recurrent
                HH[q][1][smp][64 + un] = ll;
                if (t == T_LEN) hfin[smp][un] = hv;
            }
        }

        if (stg && t + 1 < T_LEN) {            // stage x(t+1) into XH[q]
            u16 hh, ll; split_tr(xcur, hh, ll);
            XH[q][0][xs][xj] = hh; XH[q][1][xs][xj] = ll;
        }
        xcur = xnext;
        __syncthreads();
    }
#undef MFMA

    // ---- FC head: waves 0-7, wave w reduces sample w ----
    if (w < 8) {
        float v = hfin[w][l] * fc_w[l];
        #pragma unroll
        for (int off = 32; off; off >>= 1) v += __shfl_xor(v, off, 64);
        if (l == 0) out[sb + w] = v + fc_b[0];
    }
}

extern "C" void kernel_launch(void* const* d_in, const int* in_sizes, int n_in,
                              void* d_out, int out_size, void* d_ws, size_t ws_size,
                              hipStream_t stream) {
    const float* x     = (const float*)d_in[0];
    const float* W_ih0 = (const float*)d_in[1];
    const float* W_hh0 = (const float*)d_in[2];
    const float* b_ih0 = (const float*)d_in[3];
    const float* b_hh0 = (const float*)d_in[4];
    const float* W_ih1 = (const float*)d_in[5];
    const float* W_hh1 = (const float*)d_in[6];
    const float* b_ih1 = (const float*)d_in[7];
    const float* b_hh1 = (const float*)d_in[8];
    const float* fc_w  = (const float*)d_in[9];
    const float* fc_b  = (const float*)d_in[10];
    float* out = (float*)d_out;

    lstm2_mfma<<<GRID, 1024, 0, stream>>>(x, W_ih0, W_hh0, b_ih0, b_hh0,
                                          W_ih1, W_hh1, b_ih1, b_hh1,
                                          fc_w, fc_b, out);
}

// Round 8
// 278.333 us; speedup vs baseline: 10.5245x; 1.1181x over previous
//
#include <hip/hip_runtime.h>

typedef short short8 __attribute__((ext_vector_type(8)));
typedef float f32x4  __attribute__((ext_vector_type(4)));
typedef unsigned short u16;

#define T_LEN 256
#define NB    8            // samples per block
#define GRID  (2048 / NB)  // 256 blocks, 1/CU
#define LDK   136          // operand row stride in u16 (272 B)

static __device__ __forceinline__ u16 bf16_rne(float f) {
    unsigned u = __builtin_bit_cast(unsigned, f);
    return (u16)((u + 0x7fffu + ((u >> 16) & 1u)) >> 16);
}
static __device__ __forceinline__ float bf16_f(u16 h) {
    unsigned u = ((unsigned)h) << 16;
    return __builtin_bit_cast(float, u);
}
// exact trunc split: f == bf16(hi) + rest; lo = trunc-bf16(rest)
static __device__ __forceinline__ void split_tr(float f, u16& hi, u16& lo) {
    unsigned u = __builtin_bit_cast(unsigned, f);
    hi = (u16)(u >> 16);
    float rest = f - __builtin_bit_cast(float, u & 0xffff0000u);
    lo = (u16)(__builtin_bit_cast(unsigned, rest) >> 16);
}
static __device__ __forceinline__ float fast_sigmoid(float x) {
    float e = __builtin_amdgcn_exp2f(x * -1.4426950408889634f);
    return __builtin_amdgcn_rcpf(1.0f + e);
}
static __device__ __forceinline__ float fast_tanh(float x) {
    float e = __builtin_amdgcn_exp2f(x * -2.8853900817779268f);
    return 2.0f * __builtin_amdgcn_rcpf(1.0f + e) - 1.0f;
}

// ---------------------------------------------------------------------------
// 16-wave wave-specialized fused 2-layer LSTM + FC, split-bf16 MFMA with
// lo-in-columns: B operand [16][LDK] rows 0-7 = bf16-hi of samples 0-7,
// rows 8-15 = bf16-lo of samples 0-7.  Per (mt): 2 MFMA chains --
//   aH = Ah x B  (cols<8: Ah·hi, cols>=8: Ah·lo)
//   aL = Al x B + bias (cols<8: Al·hi; cols>=8 unused)
// gates(s) = aH[:,s] + aH[:,s+8] + aL[:,s].
// Half-swap via ONE __shfl_xor(8) per C row r (proven primitive, r5/r6):
//   lo-lanes send aH1+aL1 (mt1 partial incl bias), hi-lanes send aH0;
//   pk = lo8 ? aH0 + recv + aL0 : aH1 + recv.
// Waves 0-7 : layer 0, step t   (B = XH[p] = [x(t) | h1(t-1)])
// Waves 8-15: layer 1, step t-1 (B = HH[p] = [h1(t-1) | h2(t-2)])
// Row permutation (verified r4-r6): row = gate*64 + unit, unit = wl*8+mt*4+uu,
// uu = ln>>2, gate = ln&3; C: col=ln, acc[r] = gate r of unit wl*8+mt*4+kg.
// Packed lane identity: smp = ln&7, un = wl*8 + ((ln>>3)&1)*4 + kg.
// ---------------------------------------------------------------------------
__global__ __launch_bounds__(1024)
void lstm2_mfma(const float* __restrict__ x,
                const float* __restrict__ W_ih0, const float* __restrict__ W_hh0,
                const float* __restrict__ b_ih0, const float* __restrict__ b_hh0,
                const float* __restrict__ W_ih1, const float* __restrict__ W_hh1,
                const float* __restrict__ b_ih1, const float* __restrict__ b_hh1,
                const float* __restrict__ fc_w,  const float* __restrict__ fc_b,
                float* __restrict__ out)
{
    const int tid = threadIdx.x;
    const int l   = tid & 63;
    const int w   = tid >> 6;      // wave 0..15
    const int grp = w >> 3;        // 0 = layer0, 1 = layer1
    const int wl  = w & 7;         // wave-in-group 0..7
    const int ln  = l & 15;        // C col / frag row
    const int kg  = l >> 4;        // 0..3

    __shared__ __align__(16) u16 XH[2][16][LDK];   // [parity][row][k] rows: 0-7 hi, 8-15 lo
    __shared__ __align__(16) u16 HH[2][16][LDK];
    __shared__ __align__(16) float hfin[NB][68];

    // ---- A fragments (my layer, 2 mtiles): RNE hi + lo ----
    short8 Ah[2][4], Al[2][4];
    f32x4  biasv[2];
    {
        const float* Wi = grp ? W_ih1 : W_ih0;
        const float* Wh = grp ? W_hh1 : W_hh0;
        const float* bi = grp ? b_ih1 : b_ih0;
        const float* bh = grp ? b_hh1 : b_hh0;
        #pragma unroll
        for (int mt = 0; mt < 2; ++mt) {
            #pragma unroll
            for (int kt = 0; kt < 4; ++kt) {
                const int uu   = ln >> 2;
                const int gate = ln & 3;
                const int row  = gate * 64 + (wl * 8 + mt * 4 + uu);
                const int kb   = kt * 32 + kg * 8;
                const float* src = (kb < 64) ? (Wi + (size_t)row * 64 + kb)
                                             : (Wh + (size_t)row * 64 + (kb - 64));
                short8 h8, l8;
                #pragma unroll
                for (int j = 0; j < 8; ++j) {
                    float v = src[j];
                    u16 hh = bf16_rne(v);
                    u16 ll = bf16_rne(v - bf16_f(hh));
                    h8[j] = (short)hh; l8[j] = (short)ll;
                }
                Ah[mt][kt] = h8; Al[mt][kt] = l8;
            }
            f32x4 bv;
            #pragma unroll
            for (int r = 0; r < 4; ++r) {
                const int row = r * 64 + (wl * 8 + mt * 4 + kg);
                bv[r] = bi[row] + bh[row];
            }
            biasv[mt] = bv;
        }
    }

    // ---- zero operand LDS (h-state columns start at 0) ----
    {
        u16* p0 = &XH[0][0][0];
        u16* p1 = &HH[0][0][0];
        const int tot = 2 * 16 * LDK;
        for (int i = tid; i < tot; i += 1024) { p0[i] = 0; p1[i] = 0; }
    }
    __syncthreads();

    const int    sb    = blockIdx.x * NB;
    const int    xs    = (tid >> 6) & 7;   // staging sample (threads 0..511)
    const int    xj    = tid & 63;
    const bool   stg   = (tid < 512);      // wave-uniform
    const size_t xbase = ((size_t)(sb + xs)) * T_LEN * 64 + xj;

    if (stg) {   // stage x(0) into XH[0]
        u16 hh, ll; split_tr(x[xbase], hh, ll);
        XH[0][xs][xj]     = hh;
        XH[0][8 + xs][xj] = ll;
    }
    __syncthreads();

    // packed-lane identity for activations/updates
    const int  mtl  = (ln >> 3) & 1;       // 0: mt0 value, 1: mt1 value
    const int  smp  = ln & 7;              // sample
    const int  un   = wl * 8 + mtl * 4 + kg;
    const bool lo8  = (ln < 8);
    float cstate = 0.f;
    float xcur = stg ? x[xbase + 64] : 0.f;   // x(1)

#define MFMA(A, B, C) __builtin_amdgcn_mfma_f32_16x16x32_bf16(A, B, C, 0, 0, 0)

    #pragma unroll 1
    for (int t = 0; t <= T_LEN; ++t) {
        const int p = t & 1, q = p ^ 1;
        float xnext = 0.f;
        if (stg && t + 2 < T_LEN) xnext = x[xbase + (size_t)(t + 2) * 64];

        const bool active = grp ? (t >= 1) : (t < T_LEN);
        if (active) {
            const u16 (*Bv)[LDK] = grp ? HH[p] : XH[p];
            short8 b[4];
            #pragma unroll
            for (int kt = 0; kt < 4; ++kt)
                b[kt] = *(const short8*)&Bv[ln][kt * 32 + kg * 8];

            // 4 independent MFMA chains of depth 4
            f32x4 aH0 = {0.f, 0.f, 0.f, 0.f}, aH1 = {0.f, 0.f, 0.f, 0.f};
            f32x4 aL0 = biasv[0],             aL1 = biasv[1];
            #pragma unroll
            for (int kt = 0; kt < 4; ++kt) {
                aH0 = MFMA(Ah[0][kt], b[kt], aH0);
                aH1 = MFMA(Ah[1][kt], b[kt], aH1);
                aL0 = MFMA(Al[0][kt], b[kt], aL0);
                aL1 = MFMA(Al[1][kt], b[kt], aL1);
            }
            // combine hi+lo columns and pack mt1 into lanes ln>=8.
            // lo-lane a sends mt1's partial (aH1+aL1, incl bias);
            // hi-lane b sends mt0's lo-product aH0.  One shfl_xor per r.
            f32x4 pk;
            #pragma unroll
            for (int r = 0; r < 4; ++r) {
                float send = lo8 ? (aH1[r] + aL1[r]) : aH0[r];
                float recv = __shfl_xor(send, 8, 64);
                pk[r] = lo8 ? (aH0[r] + recv + aL0[r])   // mt0, sample ln
                            : (aH1[r] + recv);           // mt1, sample ln-8
            }
            const float ig = fast_sigmoid(pk[0]);
            const float fg = fast_sigmoid(pk[1]);
            const float gg = fast_tanh(pk[2]);
            const float og = fast_sigmoid(pk[3]);
            const float cc = fg * cstate + ig * gg;
            cstate = cc;
            const float hv = og * fast_tanh(cc);

            u16 hh, ll; split_tr(hv, hh, ll);
            if (grp == 0) {
                XH[q][smp][64 + un]     = hh;   // h1 recurrent (layer 0, t+1)
                XH[q][8 + smp][64 + un] = ll;
                HH[q][smp][un]          = hh;   // h1 input (layer 1, t+1)
                HH[q][8 + smp][un]      = ll;
            } else {
                HH[q][smp][64 + un]     = hh;   // h2 recurrent
                HH[q][8 + smp][64 + un] = ll;
                if (t == T_LEN) hfin[smp][un] = hv;
            }
        }

        if (stg && t + 1 < T_LEN) {            // stage x(t+1) into XH[q]
            u16 hh, ll; split_tr(xcur, hh, ll);
            XH[q][xs][xj]     = hh;
            XH[q][8 + xs][xj] = ll;
        }
        xcur = xnext;
        __syncthreads();
    }
#undef MFMA

    // ---- FC head: waves 0-7, wave w reduces sample w ----
    if (w < 8) {
        float v = hfin[w][l] * fc_w[l];
        #pragma unroll
        for (int off = 32; off; off >>= 1) v += __shfl_xor(v, off, 64);
        if (l == 0) out[sb + w] = v + fc_b[0];
    }
}

extern "C" void kernel_launch(void* const* d_in, const int* in_sizes, int n_in,
                              void* d_out, int out_size, void* d_ws, size_t ws_size,
                              hipStream_t stream) {
    const float* x     = (const float*)d_in[0];
    const float* W_ih0 = (const float*)d_in[1];
    const float* W_hh0 = (const float*)d_in[2];
    const float* b_ih0 = (const float*)d_in[3];
    const float* b_hh0 = (const float*)d_in[4];
    const float* W_ih1 = (const float*)d_in[5];
    const float* W_hh1 = (const float*)d_in[6];
    const float* b_ih1 = (const float*)d_in[7];
    const float* b_hh1 = (const float*)d_in[8];
    const float* fc_w  = (const float*)d_in[9];
    const float* fc_b  = (const float*)d_in[10];
    float* out = (float*)d_out;

    lstm2_mfma<<<GRID, 1024, 0, stream>>>(x, W_ih0, W_hh0, b_ih0, b_hh0,
                                          W_ih1, W_hh1, b_ih1, b_hh1,
                                          fc_w, fc_b, out);
}